// Round 1
// baseline (1960.346 us; speedup 1.0000x reference)
//
#include <hip/hip_runtime.h>
#include <hip/hip_bf16.h>
#include <stdint.h>

#define D_ 512
#define V_ 8192
#define B_ 2
#define T_ 256
#define U_ 64
#define M_ (B_*T_*U_)   /* 32768 rows of the big GEMM */
#define BT_ (B_*T_)     /* 512  */
#define BU_ (B_*U_)     /* 128  */

typedef __bf16 bf16x8 __attribute__((ext_vector_type(8)));
typedef float  floatx4 __attribute__((ext_vector_type(4)));

// async global->LDS, 16B per lane. LDS dst must be wave-uniform base + lane*16.
__device__ inline void load16_lds(const void* g, void* l) {
  __builtin_amdgcn_global_load_lds(
      (const __attribute__((address_space(1))) uint32_t*)(uintptr_t)g,
      (__attribute__((address_space(3))) uint32_t*)(uintptr_t)l,
      16, 0, 0);
}

// ---------------- K1: enc = v@W1+b1 (512 rows), dec = t@W2+b2 (128 rows), fp32 out
__global__ __launch_bounds__(256) void encdec_kernel(
    const float* __restrict__ v, const float* __restrict__ t,
    const float* __restrict__ W1, const float* __restrict__ b1,
    const float* __restrict__ W2, const float* __restrict__ b2,
    float* __restrict__ enc, float* __restrict__ dec) {
  __shared__ float xs[D_];
  int r = blockIdx.x;
  const float* x; const float* W; const float* bias; float* out;
  if (r < BT_) { x = v + (size_t)r*D_;          W = W1; bias = b1; out = enc + (size_t)r*D_; }
  else         { int rr = r - BT_;
                 x = t + (size_t)rr*D_;         W = W2; bias = b2; out = dec + (size_t)rr*D_; }
  int tid = threadIdx.x;
  xs[tid]       = x[tid];
  xs[tid + 256] = x[tid + 256];
  __syncthreads();
  float a0 = 0.f, a1 = 0.f;
  int c0 = tid * 2;
  #pragma unroll 8
  for (int k = 0; k < D_; ++k) {
    float xv = xs[k];
    float2 w = *(const float2*)(W + (size_t)k*D_ + c0);
    a0 += xv * w.x;
    a1 += xv * w.y;
  }
  float2 o; o.x = a0 + bias[c0]; o.y = a1 + bias[c0+1];
  *(float2*)(out + c0) = o;
}

// ---------------- K1b: WvT[n][k] = bf16(Wv[k][n])  (512x8192 -> 8192x512)
__global__ __launch_bounds__(256) void wv_transpose_kernel(
    const float* __restrict__ Wv, __bf16* __restrict__ WvT) {
  __shared__ float tile[64][65];
  int k0 = (blockIdx.x & 7) * 64;    // 512/64 = 8 k-tiles
  int n0 = (blockIdx.x >> 3) * 64;   // 8192/64 = 128 n-tiles
  int tid = threadIdx.x;
  int c  = tid & 63;
  int r0 = tid >> 6;                 // 0..3
  #pragma unroll
  for (int i = 0; i < 64; i += 4)
    tile[r0 + i][c] = Wv[(size_t)(k0 + r0 + i) * V_ + n0 + c];
  __syncthreads();
  #pragma unroll
  for (int i = 0; i < 64; i += 4)
    WvT[(size_t)(n0 + r0 + i) * D_ + k0 + c] = (__bf16)tile[c][r0 + i];
}

// ---------------- K1c: h[m][k] = bf16(relu(enc[bt][k] + dec[b*64+u][k]))
__global__ __launch_bounds__(256) void build_h_kernel(
    const float* __restrict__ enc, const float* __restrict__ dec,
    __bf16* __restrict__ h) {
  int tid = blockIdx.x * 256 + threadIdx.x;  // 0 .. 2M-1 (8 elems each)
  int m  = tid >> 6;
  int kc = (tid & 63) << 3;
  int bt = m >> 6;
  int dr = ((m >> 14) << 6) | (m & 63);
  const float4* e4 = (const float4*)(enc + (size_t)bt*D_ + kc);
  const float4* d4 = (const float4*)(dec + (size_t)dr*D_ + kc);
  float4 e0 = e4[0], e1 = e4[1];
  float4 d0 = d4[0], d1 = d4[1];
  bf16x8 o;
  o[0] = (__bf16)fmaxf(e0.x + d0.x, 0.f);
  o[1] = (__bf16)fmaxf(e0.y + d0.y, 0.f);
  o[2] = (__bf16)fmaxf(e0.z + d0.z, 0.f);
  o[3] = (__bf16)fmaxf(e0.w + d0.w, 0.f);
  o[4] = (__bf16)fmaxf(e1.x + d1.x, 0.f);
  o[5] = (__bf16)fmaxf(e1.y + d1.y, 0.f);
  o[6] = (__bf16)fmaxf(e1.z + d1.z, 0.f);
  o[7] = (__bf16)fmaxf(e1.w + d1.w, 0.f);
  *(bf16x8*)(h + (size_t)m*D_ + kc) = o;
}

// ---------------- K2: logits = h @ WvT^T + bv -> d_out; atomic per-row sum(exp)
#define BM 128
#define BN 128
#define BKk 64

__global__ __launch_bounds__(256) void gemm_kernel(
    const __bf16* __restrict__ h, const __bf16* __restrict__ WvT,
    const float* __restrict__ bv, float* __restrict__ out,
    float* __restrict__ lse) {
  // XOR-swizzled chunk layout: slot s=(r*8+sc) holds row r, k-chunk c = sc^(r&7)
  __shared__ __bf16 As[BM * BKk];
  __shared__ __bf16 Bs[BN * BKk];
  const int tid  = threadIdx.x;
  const int lane = tid & 63;
  const int w    = tid >> 6;       // 4 waves: 2x2
  const int wm   = w & 1, wn = w >> 1;
  const int bid  = blockIdx.x;
  const int gm0  = (bid & 255) * BM;   // 256 m-tiles (consecutive bids share n-tile)
  const int gn0  = (bid >> 8) * BN;    // 64 n-tiles
  const int quad = lane >> 4;
  const int l15  = lane & 15;
  const int key  = lane & 7;

  floatx4 acc[4][4];
  #pragma unroll
  for (int a = 0; a < 4; ++a)
    #pragma unroll
    for (int b = 0; b < 4; ++b)
      acc[a][b] = (floatx4){0.f, 0.f, 0.f, 0.f};

  for (int ki = 0; ki < D_/BKk; ++ki) {
    const int k0 = ki * BKk;
    #pragma unroll
    for (int i = 0; i < 4; ++i) {
      int s = i * 256 + tid;
      int r = s >> 3;
      int c = (s & 7) ^ (r & 7);
      load16_lds(h   + (size_t)(gm0 + r)*D_ + k0 + c*8, As + s*8);
      load16_lds(WvT + (size_t)(gn0 + r)*D_ + k0 + c*8, Bs + s*8);
    }
    __syncthreads();   // compiler drains vmcnt before s_barrier
    #pragma unroll
    for (int kk = 0; kk < 2; ++kk) {
      bf16x8 af[4], bfr[4];
      const int cslot = (kk*4 + quad) ^ key;
      #pragma unroll
      for (int mt = 0; mt < 4; ++mt) {
        int r = wm*64 + mt*16 + l15;
        af[mt] = *(const bf16x8*)(As + (r*8 + cslot)*8);
      }
      #pragma unroll
      for (int nt = 0; nt < 4; ++nt) {
        int r = wn*64 + nt*16 + l15;
        bfr[nt] = *(const bf16x8*)(Bs + (r*8 + cslot)*8);
      }
      #pragma unroll
      for (int mt = 0; mt < 4; ++mt)
        #pragma unroll
        for (int nt = 0; nt < 4; ++nt)
          acc[mt][nt] = __builtin_amdgcn_mfma_f32_16x16x32_bf16(
              af[mt], bfr[nt], acc[mt][nt], 0, 0, 0);
    }
    __syncthreads();
  }

  // epilogue: bias, store logits, per-row sum(exp) -> atomicAdd
  float bvv[4];
  #pragma unroll
  for (int nt = 0; nt < 4; ++nt)
    bvv[nt] = bv[gn0 + wn*64 + nt*16 + l15];

  #pragma unroll
  for (int mt = 0; mt < 4; ++mt) {
    const int rg = gm0 + wm*64 + mt*16 + quad*4;  // + i
    #pragma unroll
    for (int i = 0; i < 4; ++i) {
      float s = 0.f;
      #pragma unroll
      for (int nt = 0; nt < 4; ++nt) {
        float lg = acc[mt][nt][i] + bvv[nt];
        out[(size_t)(rg + i)*V_ + gn0 + wn*64 + nt*16 + l15] = lg;
        s += exp2f(lg * 1.44269504088896f);   // e^lg
      }
      #pragma unroll
      for (int off = 1; off < 16; off <<= 1)
        s += __shfl_xor(s, off, 64);          // reduce across l15 (quad preserved)
      if (l15 == 0) atomicAdd(&lse[rg + i], s);
    }
  }
}

// ---------------- K2.5: lse -> log(lse)
__global__ __launch_bounds__(256) void lse_log_kernel(float* lse) {
  int i = blockIdx.x * 256 + threadIdx.x;
  lse[i] = logf(lse[i]);
}

// ---------------- K3: out -= log-sum-exp of its row
__global__ __launch_bounds__(256) void subtract_kernel(
    float4* __restrict__ out4, const float* __restrict__ lse) {
  const long long n4 = (long long)M_ * V_ / 4;  // 64M float4
  long long i = (long long)blockIdx.x * 256 + threadIdx.x;
  const long long stride = (long long)gridDim.x * 256;
  for (; i < n4; i += stride) {
    int row = (int)(i >> 11);                   // 2048 float4 per row
    float l = lse[row];
    float4 vv = out4[i];
    vv.x -= l; vv.y -= l; vv.z -= l; vv.w -= l;
    out4[i] = vv;
  }
}

extern "C" void kernel_launch(void* const* d_in, const int* in_sizes, int n_in,
                              void* d_out, int out_size, void* d_ws, size_t ws_size,
                              hipStream_t stream) {
  const float* v  = (const float*)d_in[0];
  const float* t  = (const float*)d_in[1];
  const float* W1 = (const float*)d_in[2];
  const float* b1 = (const float*)d_in[3];
  const float* W2 = (const float*)d_in[4];
  const float* b2 = (const float*)d_in[5];
  const float* Wv = (const float*)d_in[6];
  const float* bv = (const float*)d_in[7];
  float* out = (float*)d_out;

  char* ws = (char*)d_ws;
  float*  enc = (float*)(ws);                              // 1 MB
  float*  dec = (float*)(ws + (1u<<20));                   // 256 KB
  float*  lse = (float*)(ws + (1u<<20) + (256u<<10));      // 128 KB
  __bf16* WvT = (__bf16*)(ws + (2u<<20));                  // 8 MB
  __bf16* h   = (__bf16*)(ws + (10u<<20));                 // 32 MB  (total 42 MB)

  hipMemsetAsync(lse, 0, M_*sizeof(float), stream);
  encdec_kernel<<<BT_ + BU_, 256, 0, stream>>>(v, t, W1, b1, W2, b2, enc, dec);
  wv_transpose_kernel<<<1024, 256, 0, stream>>>(Wv, WvT);
  build_h_kernel<<<(M_*D_/8)/256, 256, 0, stream>>>(enc, dec, h);
  gemm_kernel<<<(M_/BM)*(V_/BN), 256, 0, stream>>>(h, WvT, bv, out, lse);
  lse_log_kernel<<<M_/256, 256, 0, stream>>>(lse);
  subtract_kernel<<<8192, 256, 0, stream>>>((float4*)out, lse);
}